// Round 11
// baseline (415.016 us; speedup 1.0000x reference)
//
#include <hip/hip_runtime.h>
#include <hip/hip_fp16.h>

#define N_NODES 100000
#define N_EDGES 1000000
#define C_IN 128
#define C_HID 64
#define C_OUT 32
#define GT_BLOCKS 1563                   // gemm1 tiles of 64 rows (ceil(1e5/64))
#define RG_RANK_BLOCKS 781               // rank blocks inside k_rg1
#define RG_GRID 2344                     // 3*781+1: tiles t=2r+m (m<2), rank r (m==2)
#define AGG1_BLOCKS 6250                 // 4 waves/block -> 4 nodes per wave
#define SF_BLOCKS 196                    // scanfill: 196 x 512 thr, all co-resident
#define SF_NPB 512                       // nodes per scanfill block (196*512 >= 1e5)

// ---------------------------------------------------------------------------
// FUSED rank ∥ gemm1 (independent work, co-resident block populations).
// Unchanged from R10 (passing, 65 us).
// ---------------------------------------------------------------------------
__global__ __launch_bounds__(256) void k_rg1(const unsigned int* __restrict__ ei,
                                             int* __restrict__ deg,
                                             int* __restrict__ rank,
                                             const float* __restrict__ x,
                                             const float* __restrict__ W1,
                                             __half* __restrict__ hs1h) {
    __shared__ float xt[64 * C_IN];     // 32 KB
    const int bid = blockIdx.x;
    const int m = bid % 3;
    const int r = bid / 3;

    if (m == 2) {
        // ----- rank block r of RG_RANK_BLOCKS -----
        const bool is64 = __all(ei[2 * (threadIdx.x & 63) + 1] == 0u);
        const int T = RG_RANK_BLOCKS * 256;
        const int t = r * 256 + threadIdx.x;
        int d[6];
#pragma unroll
        for (int i = 0; i < 6; ++i) {
            int e = t + i * T;
            if (e < N_EDGES)
                d[i] = is64 ? ((const int2*)ei)[(size_t)N_EDGES + e].x
                            : (int)ei[(size_t)N_EDGES + e];
        }
        int rk[6];
#pragma unroll
        for (int i = 0; i < 6; ++i) {
            int e = t + i * T;
            if (e < N_EDGES) rk[i] = atomicAdd(&deg[d[i]], 1);
        }
#pragma unroll
        for (int i = 0; i < 6; ++i) {
            int e = t + i * T;
            if (e < N_EDGES) __builtin_nontemporal_store(rk[i], &rank[e]);
        }
        return;
    }

    // ----- gemm tile t = 2r+m of GT_BLOCKS -----
    const int tile = 2 * r + m;
    if (tile >= GT_BLOCKS) return;
    const int t = threadIdx.x;
    {
        const float4* x4g = (const float4*)x;
        float4* xt4w = (float4*)xt;
        const size_t base = (size_t)tile * 64 * (C_IN / 4);
        const size_t xmax = (size_t)N_NODES * (C_IN / 4) - 1;
#pragma unroll
        for (int j = 0; j < 8; ++j) {
            size_t idx = base + t + j * 256;
            if (idx > xmax) idx = xmax;            // tail clamp (dup reads ok)
            xt4w[t + j * 256] = x4g[idx];
        }
    }
    __syncthreads();
    const int c2 = t & 31;          // channel pair
    const int h  = (t >> 5) & 1;    // half-wave -> row group
    const int wid = t >> 6;
    const int lrow0 = wid * 16 + h * 8;
    const int grow0 = tile * 64 + lrow0;
    const float4* xt4 = (const float4*)xt;

    float acc0[8] = {0, 0, 0, 0, 0, 0, 0, 0};
    float acc1[8] = {0, 0, 0, 0, 0, 0, 0, 0};
#pragma unroll 2
    for (int k4 = 0; k4 < C_IN / 4; ++k4) {
        float4 xv[8];
#pragma unroll
        for (int rr = 0; rr < 8; ++rr)
            xv[rr] = xt4[(lrow0 + rr) * (C_IN / 4) + k4];   // LDS broadcast
        float2 wv[4];
#pragma unroll
        for (int j = 0; j < 4; ++j)
            wv[j] = *reinterpret_cast<const float2*>(&W1[(k4 * 4 + j) * C_HID + 2 * c2]);
#pragma unroll
        for (int rr = 0; rr < 8; ++rr) {
            acc0[rr] = fmaf(xv[rr].x, wv[0].x, acc0[rr]);
            acc1[rr] = fmaf(xv[rr].x, wv[0].y, acc1[rr]);
            acc0[rr] = fmaf(xv[rr].y, wv[1].x, acc0[rr]);
            acc1[rr] = fmaf(xv[rr].y, wv[1].y, acc1[rr]);
            acc0[rr] = fmaf(xv[rr].z, wv[2].x, acc0[rr]);
            acc1[rr] = fmaf(xv[rr].z, wv[2].y, acc1[rr]);
            acc0[rr] = fmaf(xv[rr].w, wv[3].x, acc0[rr]);
            acc1[rr] = fmaf(xv[rr].w, wv[3].y, acc1[rr]);
        }
    }
    __half2* h2o = (__half2*)hs1h;
#pragma unroll
    for (int rr = 0; rr < 8; ++rr) {
        int gr = grow0 + rr;
        if (gr < N_NODES)
            h2o[(size_t)gr * 32 + c2] = __floats2half2_rn(acc0[rr], acc1[rr]);
    }
}

// ---------------------------------------------------------------------------
// Software grid barrier for co-resident grids (196 blocks << 256 CUs, so all
// blocks are resident before any can spin -> no dispatch-order dependence).
// Device-scope atomics + threadfence for cross-XCD visibility (G16).
// ---------------------------------------------------------------------------
__device__ __forceinline__ void gbar(int* cnt, int n) {
    __threadfence();                 // release: prior writes visible device-wide
    __syncthreads();
    if (threadIdx.x == 0) {
        atomicAdd(cnt, 1);
        while (atomicAdd(cnt, 0) < n) __builtin_amdgcn_s_sleep(1);
    }
    __syncthreads();
    __threadfence();                 // acquire: subsequent reads see all writes
}

// ---------------------------------------------------------------------------
// FUSED CSR offsets + fill (replaces scan1+scan2+scan3+fill2 = 4 dispatches;
// R10 totals arithmetic: ~10 us overhead PER dispatch => fusion > splitting).
//  A: per-block scan of deg slice (+dinv)  | bar
//     block 0 scans the 196 block sums     | bar
//     rowstart = local + blockoff          | bar (fence: random reads follow)
//  B: fill: esrc[rowstart[dst]+rank[e]] = src  (grid-stride, 4-wide ILP, NT)
// ---------------------------------------------------------------------------
__global__ __launch_bounds__(512) void k_scanfill(const unsigned int* __restrict__ ei,
                                                  const int* __restrict__ deg,
                                                  const int* __restrict__ rank,
                                                  int* __restrict__ rowstart,
                                                  float* __restrict__ dinv,
                                                  int* __restrict__ esrc,
                                                  int* __restrict__ blksum,
                                                  int* __restrict__ barcnt) {
    __shared__ int sm[SF_NPB];
    const int b = blockIdx.x;
    const int t = threadIdx.x;
    const int i = b * SF_NPB + t;

    // --- phase A: local exclusive scan + dinv ---
    int v = (i < N_NODES) ? deg[i] : 0;
    if (i < N_NODES) dinv[i] = rsqrtf((float)v + 1.0f);
    sm[t] = v;
    __syncthreads();
    for (int o = 1; o < SF_NPB; o <<= 1) {
        int u = (t >= o) ? sm[t - o] : 0;
        __syncthreads();
        sm[t] += u;
        __syncthreads();
    }
    const int local_excl = sm[t] - v;
    if (t == SF_NPB - 1) blksum[b] = sm[SF_NPB - 1];

    gbar(barcnt + 0, SF_BLOCKS);

    if (b == 0) {   // scan the 196 block sums (fits one 512-wide block scan)
        int s = (t < SF_BLOCKS) ? blksum[t] : 0;
        sm[t] = s;
        __syncthreads();
        for (int o = 1; o < SF_NPB; o <<= 1) {
            int u = (t >= o) ? sm[t - o] : 0;
            __syncthreads();
            sm[t] += u;
            __syncthreads();
        }
        if (t < SF_BLOCKS) blksum[t] = sm[t] - s;   // exclusive block offsets
    }

    gbar(barcnt + 1, SF_BLOCKS);

    if (i < N_NODES) rowstart[i] = local_excl + blksum[b];
    if (i == 0) rowstart[N_NODES] = N_EDGES;

    gbar(barcnt + 2, SF_BLOCKS);    // fence inside: random rowstart reads next

    // --- phase B: fill ---
    const bool is64 = __all(ei[2 * (t & 63) + 1] == 0u);
    const int T = SF_BLOCKS * SF_NPB;        // 100352
    for (int base = b * SF_NPB + t; base < N_EDGES; base += 4 * T) {
        int e[4], s[4], d[4], p[4];
#pragma unroll
        for (int k = 0; k < 4; ++k) {
            e[k] = base + k * T;
            int ec = (e[k] < N_EDGES) ? e[k] : 0;
            if (is64) {
                s[k] = ((const int2*)ei)[ec].x;
                d[k] = ((const int2*)ei)[(size_t)N_EDGES + ec].x;
            } else {
                s[k] = (int)ei[ec];
                d[k] = (int)ei[(size_t)N_EDGES + ec];
            }
        }
#pragma unroll
        for (int k = 0; k < 4; ++k)
            p[k] = rowstart[d[k]] + rank[(e[k] < N_EDGES) ? e[k] : 0];
#pragma unroll
        for (int k = 0; k < 4; ++k)
            if (e[k] < N_EDGES) __builtin_nontemporal_store(s[k], &esrc[p[k]]);
    }
}

// ---------------------------------------------------------------------------
// FUSED agg1 + layer-1 epilogue + GEMM2. Unchanged from R10 (passing).
// ---------------------------------------------------------------------------
__global__ __launch_bounds__(256) void k_agg1g2(const int* __restrict__ rowstart,
                                                const int* __restrict__ esrc,
                                                const __half* __restrict__ hs1h,
                                                const float* __restrict__ dinv,
                                                const float* __restrict__ b1,
                                                const float* __restrict__ W2,
                                                __half* __restrict__ hs2h) {
    __shared__ float2 yrow[4][32];      // per-wave y-row buffer
    const int wid = threadIdx.x >> 6;
    const int lane = threadIdx.x & 63;
    const int c2 = lane & 31;           // layer1 channel-pair; layer2 out-channel
    const int eo = lane >> 5;           // half-wave index
    float Wreg[32];
#pragma unroll
    for (int kk = 0; kk < 16; ++kk) {
        Wreg[2 * kk]     = W2[(32 * eo + 2 * kk) * C_OUT + c2];
        Wreg[2 * kk + 1] = W2[(32 * eo + 2 * kk + 1) * C_OUT + c2];
    }
    const __half2* h2 = (const __half2*)hs1h;
    const float2 bb = { b1[2 * c2], b1[2 * c2 + 1] };
    const int waveId = blockIdx.x * 4 + wid;

    for (int node = waveId; node < N_NODES; node += AGG1_BLOCKS * 4) {
        const int beg = rowstart[node], end = rowstart[node + 1];
        float2 acc; acc.x = 0.f; acc.y = 0.f;
        for (int j0 = beg; j0 < end; j0 += 16) {
            const int jj = j0 + eo;
            int idx[8];
#pragma unroll
            for (int s = 0; s < 8; ++s) {
                int j = jj + 2 * s;
                idx[s] = esrc[j < end ? j : beg];   // clamp: dup load, L1 hit
            }
            float ds[8];
#pragma unroll
            for (int s = 0; s < 8; ++s)
                ds[s] = (jj + 2 * s < end) ? dinv[idx[s]] : 0.f;  // predicate via 0-scale
            float2 v[8];
#pragma unroll
            for (int s = 0; s < 8; ++s)
                v[s] = __half22float2(h2[(size_t)idx[s] * 32 + c2]);
#pragma unroll
            for (int s = 0; s < 8; ++s) {
                acc.x = fmaf(ds[s], v[s].x, acc.x);
                acc.y = fmaf(ds[s], v[s].y, acc.y);
            }
        }
        acc.x += __shfl_xor(acc.x, 32);
        acc.y += __shfl_xor(acc.y, 32);
        // layer-1 epilogue: y = relu(dv*(acc + dv*self) + b)
        const float dv = dinv[node];
        float2 self = __half22float2(h2[(size_t)node * 32 + c2]);
        float2 y;
        y.x = fmaxf(fmaf(dv, fmaf(dv, self.x, acc.x), bb.x), 0.f);
        y.y = fmaxf(fmaf(dv, fmaf(dv, self.y, acc.y), bb.y), 0.f);
        yrow[wid][c2] = y;              // both halves write same value (benign)
        __builtin_amdgcn_wave_barrier();
        // layer-2 matvec: out[c2] = Σ_k y[k] * W2[k][c2], k-half per eo
        float o = 0.f;
#pragma unroll
        for (int kk = 0; kk < 16; ++kk) {
            float2 yv = yrow[wid][16 * eo + kk];
            o = fmaf(yv.x, Wreg[2 * kk], o);
            o = fmaf(yv.y, Wreg[2 * kk + 1], o);
        }
        __builtin_amdgcn_wave_barrier();
        o += __shfl_xor(o, 32);
        if (eo == 0)
            hs2h[(size_t)node * C_OUT + c2] = __float2half(o * dv);
    }
}

// ---------------------------------------------------------------------------
// Agg2 (+fused epilogue, no relu). Unchanged from R10 (passing).
// ---------------------------------------------------------------------------
__global__ __launch_bounds__(256) void k_agg2(const int* __restrict__ rowstart,
                                              const int* __restrict__ esrc,
                                              const __half* __restrict__ hs2h,
                                              const float* __restrict__ dinv,
                                              const float* __restrict__ b2,
                                              float* __restrict__ out) {
    const int node = blockIdx.x * 4 + (threadIdx.x >> 6);
    const int lane = threadIdx.x & 63;
    const int c2 = lane & 15;
    const int eo = lane >> 4;
    const __half2* h2 = (const __half2*)hs2h;
    const int beg = rowstart[node], end = rowstart[node + 1];
    float2 acc; acc.x = 0.f; acc.y = 0.f;
    for (int j0 = beg; j0 < end; j0 += 16) {
        const int jj = j0 + eo;
        int idx[4];
#pragma unroll
        for (int s = 0; s < 4; ++s) {
            int j = jj + 4 * s;
            idx[s] = esrc[j < end ? j : beg];
        }
        float2 v[4];
#pragma unroll
        for (int s = 0; s < 4; ++s)
            v[s] = __half22float2(h2[(size_t)idx[s] * 16 + c2]);
#pragma unroll
        for (int s = 0; s < 4; ++s) {
            if (jj + 4 * s < end) { acc.x += v[s].x; acc.y += v[s].y; }
        }
    }
    acc.x += __shfl_xor(acc.x, 16);
    acc.y += __shfl_xor(acc.y, 16);
    acc.x += __shfl_xor(acc.x, 32);
    acc.y += __shfl_xor(acc.y, 32);
    if (eo == 0) {
        float2 self = __half22float2(h2[(size_t)node * 16 + c2]);
        float dv = dinv[node];
        float2 o;
        o.x = fmaf(dv, acc.x + self.x, b2[2 * c2]);
        o.y = fmaf(dv, acc.y + self.y, b2[2 * c2 + 1]);
        reinterpret_cast<float2*>(out)[(size_t)node * 16 + c2] = o;
    }
}

extern "C" void kernel_launch(void* const* d_in, const int* in_sizes, int n_in,
                              void* d_out, int out_size, void* d_ws, size_t ws_size,
                              hipStream_t stream) {
    const float* x  = (const float*)d_in[0];
    const unsigned int* ei = (const unsigned int*)d_in[1];
    const float* W1 = (const float*)d_in[2];
    const float* b1 = (const float*)d_in[3];
    const float* W2 = (const float*)d_in[4];
    const float* b2 = (const float*)d_in[5];
    float* out = (float*)d_out;

    char* ws = (char*)d_ws;
    size_t off = 0;
    auto take = [&](size_t bytes) {
        char* p = ws + off;
        off += (bytes + 255) & ~(size_t)255;
        return p;
    };
    int*    esrc     = (int*)   take((size_t)N_EDGES * 4);
    int*    rank     = (int*)   take((size_t)N_EDGES * 4);
    int*    degz     = (int*)   take((size_t)N_NODES * 4 + 256); // deg + barrier counters
    int*    deg      = degz;
    int*    barcnt   = degz + N_NODES;                           // 3 counters, zeroed with deg
    int*    rowstart = (int*)   take((size_t)(N_NODES + 1) * 4);
    int*    blksum   = (int*)   take(256 * 4);
    float*  dinv     = (float*) take((size_t)N_NODES * 4);
    __half* hs1h     = (__half*)take((size_t)N_NODES * C_HID * 2);
    __half* hs2h     = (__half*)take((size_t)N_NODES * C_OUT * 2);

    // op1: zero deg + barrier counters (one region, one memset)
    hipMemsetAsync(degz, 0, (size_t)N_NODES * 4 + 256, stream);

    // op2: rank ∥ gemm1 (independent; co-resident block populations)
    k_rg1<<<RG_GRID, 256, 0, stream>>>(ei, deg, rank, x, W1, hs1h);

    // op3: CSR offsets + fill in ONE kernel (software grid barriers)
    k_scanfill<<<SF_BLOCKS, 512, 0, stream>>>(ei, deg, rank, rowstart, dinv,
                                              esrc, blksum, barcnt);

    // op4: agg1 + epilogue1 + gemm2  (y1 never hits global memory)
    k_agg1g2<<<AGG1_BLOCKS, 256, 0, stream>>>(rowstart, esrc, hs1h, dinv, b1, W2, hs2h);

    // op5: agg2 + epilogue
    k_agg2<<<N_NODES / 4, 256, 0, stream>>>(rowstart, esrc, hs2h, dinv, b2, out);
}

// Round 13
// 313.101 us; speedup vs baseline: 1.3255x; 1.3255x over previous
//
#include <hip/hip_runtime.h>
#include <hip/hip_fp16.h>

#define N_NODES 100000
#define N_EDGES 1000000
#define C_IN 128
#define C_HID 64
#define C_OUT 32
#define GT_BLOCKS 1563                   // gemm1 tiles of 64 rows (ceil(1e5/64))
#define RG_RANK_BLOCKS 781               // rank blocks inside k_rg1
#define RG_GRID 2344                     // 3*781+1: tiles t=2r+m (m<2), rank r (m==2)
#define AGG1_BLOCKS 6250                 // 4 waves/block -> 4 nodes per wave

// ---------------------------------------------------------------------------
// FUSED rank ∥ gemm1 (independent work, co-resident block populations).
// Unchanged from R10 (passing, 65 us).
// ---------------------------------------------------------------------------
__global__ __launch_bounds__(256) void k_rg1(const unsigned int* __restrict__ ei,
                                             int* __restrict__ deg,
                                             int* __restrict__ rank,
                                             const float* __restrict__ x,
                                             const float* __restrict__ W1,
                                             __half* __restrict__ hs1h) {
    __shared__ float xt[64 * C_IN];     // 32 KB
    const int bid = blockIdx.x;
    const int m = bid % 3;
    const int r = bid / 3;

    if (m == 2) {
        // ----- rank block r of RG_RANK_BLOCKS -----
        const bool is64 = __all(ei[2 * (threadIdx.x & 63) + 1] == 0u);
        const int T = RG_RANK_BLOCKS * 256;
        const int t = r * 256 + threadIdx.x;
        int d[6];
#pragma unroll
        for (int i = 0; i < 6; ++i) {
            int e = t + i * T;
            if (e < N_EDGES)
                d[i] = is64 ? ((const int2*)ei)[(size_t)N_EDGES + e].x
                            : (int)ei[(size_t)N_EDGES + e];
        }
        int rk[6];
#pragma unroll
        for (int i = 0; i < 6; ++i) {
            int e = t + i * T;
            if (e < N_EDGES) rk[i] = atomicAdd(&deg[d[i]], 1);
        }
#pragma unroll
        for (int i = 0; i < 6; ++i) {
            int e = t + i * T;
            if (e < N_EDGES) __builtin_nontemporal_store(rk[i], &rank[e]);
        }
        return;
    }

    // ----- gemm tile t = 2r+m of GT_BLOCKS -----
    const int tile = 2 * r + m;
    if (tile >= GT_BLOCKS) return;
    const int t = threadIdx.x;
    {
        const float4* x4g = (const float4*)x;
        float4* xt4w = (float4*)xt;
        const size_t base = (size_t)tile * 64 * (C_IN / 4);
        const size_t xmax = (size_t)N_NODES * (C_IN / 4) - 1;
#pragma unroll
        for (int j = 0; j < 8; ++j) {
            size_t idx = base + t + j * 256;
            if (idx > xmax) idx = xmax;            // tail clamp (dup reads ok)
            xt4w[t + j * 256] = x4g[idx];
        }
    }
    __syncthreads();
    const int c2 = t & 31;          // channel pair
    const int h  = (t >> 5) & 1;    // half-wave -> row group
    const int wid = t >> 6;
    const int lrow0 = wid * 16 + h * 8;
    const int grow0 = tile * 64 + lrow0;
    const float4* xt4 = (const float4*)xt;

    float acc0[8] = {0, 0, 0, 0, 0, 0, 0, 0};
    float acc1[8] = {0, 0, 0, 0, 0, 0, 0, 0};
#pragma unroll 2
    for (int k4 = 0; k4 < C_IN / 4; ++k4) {
        float4 xv[8];
#pragma unroll
        for (int rr = 0; rr < 8; ++rr)
            xv[rr] = xt4[(lrow0 + rr) * (C_IN / 4) + k4];   // LDS broadcast
        float2 wv[4];
#pragma unroll
        for (int j = 0; j < 4; ++j)
            wv[j] = *reinterpret_cast<const float2*>(&W1[(k4 * 4 + j) * C_HID + 2 * c2]);
#pragma unroll
        for (int rr = 0; rr < 8; ++rr) {
            acc0[rr] = fmaf(xv[rr].x, wv[0].x, acc0[rr]);
            acc1[rr] = fmaf(xv[rr].x, wv[0].y, acc1[rr]);
            acc0[rr] = fmaf(xv[rr].y, wv[1].x, acc0[rr]);
            acc1[rr] = fmaf(xv[rr].y, wv[1].y, acc1[rr]);
            acc0[rr] = fmaf(xv[rr].z, wv[2].x, acc0[rr]);
            acc1[rr] = fmaf(xv[rr].z, wv[2].y, acc1[rr]);
            acc0[rr] = fmaf(xv[rr].w, wv[3].x, acc0[rr]);
            acc1[rr] = fmaf(xv[rr].w, wv[3].y, acc1[rr]);
        }
    }
    __half2* h2o = (__half2*)hs1h;
#pragma unroll
    for (int rr = 0; rr < 8; ++rr) {
        int gr = grow0 + rr;
        if (gr < N_NODES)
            h2o[(size_t)gr * 32 + c2] = __floats2half2_rn(acc0[rr], acc1[rr]);
    }
}

// ---------------------------------------------------------------------------
// Single-block CSR-offset scan (replaces scan1+scan2+scan3: 3 dispatches -> 1,
// ~10us/dispatch overhead each per R6/R7/R10 fit). 1024 thr = 16 waves; wave w
// owns contiguous [w*6272, (w+1)*6272). NO cross-block sync (R11 lesson: grid
// barriers starve concurrency-hungry phases; a scan is not one -- 800KB L2).
// Pass1: wave totals -> LDS -> serial 16-scan. Pass2: coalesced wave scans.
// ---------------------------------------------------------------------------
__global__ __launch_bounds__(1024) void k_scanone(const int* __restrict__ deg,
                                                  int* __restrict__ rowstart,
                                                  float* __restrict__ dinv) {
    __shared__ int wsum[16];
    const int t = threadIdx.x;
    const int lane = t & 63;
    const int w = t >> 6;
    const int base = w * 6272;          // 16 waves x 98 rounds x 64 lanes >= 1e5
    // pass 1: wave totals
    int s = 0;
    for (int k = 0; k < 98; ++k) {
        int i = base + k * 64 + lane;
        s += (i < N_NODES) ? deg[i] : 0;
    }
#pragma unroll
    for (int o = 1; o < 64; o <<= 1) s += __shfl_xor(s, o);
    if (lane == 0) wsum[w] = s;
    __syncthreads();
    if (t == 0) {
        int run = 0;
#pragma unroll
        for (int k = 0; k < 16; ++k) { int v = wsum[k]; wsum[k] = run; run += v; }
    }
    __syncthreads();
    int rowoff = wsum[w];
    // pass 2: full exclusive scan + dinv
    for (int k = 0; k < 98; ++k) {
        int i = base + k * 64 + lane;
        int v = (i < N_NODES) ? deg[i] : 0;
        int incl = v;
#pragma unroll
        for (int o = 1; o < 64; o <<= 1) {
            int y = __shfl_up(incl, o);
            if (lane >= o) incl += y;
        }
        if (i < N_NODES) {
            rowstart[i] = rowoff + incl - v;
            dinv[i] = rsqrtf((float)v + 1.0f);
        }
        rowoff += __shfl(incl, 63);
    }
    if (t == 0) rowstart[N_NODES] = N_EDGES;
}

// ---------------------------------------------------------------------------
// Fill pass: p = rowstart[dst] + rank[e]; esrc[p] = src. No atomics; NT store.
// 1024 blocks (262K threads): the scattered-store path is concurrency-hungry
// (R11: 196 blocks -> 7x slower). Unchanged from R10.
// ---------------------------------------------------------------------------
__global__ __launch_bounds__(256) void k_fill2(const unsigned int* __restrict__ ei,
                                               const int* __restrict__ rowstart,
                                               const int* __restrict__ rank,
                                               int* __restrict__ esrc) {
    const bool is64 = __all(ei[2 * (threadIdx.x & 63) + 1] == 0u);
    const int T = gridDim.x * 256;
    const int t = blockIdx.x * 256 + threadIdx.x;
#pragma unroll
    for (int i = 0; i < 4; ++i) {
        int e = t + i * T;
        if (e < N_EDGES) {
            int s, d;
            if (is64) {
                s = ((const int2*)ei)[e].x;
                d = ((const int2*)ei)[(size_t)N_EDGES + e].x;
            } else {
                s = (int)ei[e];
                d = (int)ei[(size_t)N_EDGES + e];
            }
            int p = rowstart[d] + rank[e];
            __builtin_nontemporal_store(s, &esrc[p]);
        }
    }
}

// ---------------------------------------------------------------------------
// FUSED agg1 + layer-1 epilogue + GEMM2. Unchanged from R10 (passing; at the
// ~36-40 G random-lines/s device gather ceiling: 2 lines/edge, 56 us).
// ---------------------------------------------------------------------------
__global__ __launch_bounds__(256) void k_agg1g2(const int* __restrict__ rowstart,
                                                const int* __restrict__ esrc,
                                                const __half* __restrict__ hs1h,
                                                const float* __restrict__ dinv,
                                                const float* __restrict__ b1,
                                                const float* __restrict__ W2,
                                                __half* __restrict__ hs2h) {
    __shared__ float2 yrow[4][32];      // per-wave y-row buffer
    const int wid = threadIdx.x >> 6;
    const int lane = threadIdx.x & 63;
    const int c2 = lane & 31;           // layer1 channel-pair; layer2 out-channel
    const int eo = lane >> 5;           // half-wave index
    float Wreg[32];
#pragma unroll
    for (int kk = 0; kk < 16; ++kk) {
        Wreg[2 * kk]     = W2[(32 * eo + 2 * kk) * C_OUT + c2];
        Wreg[2 * kk + 1] = W2[(32 * eo + 2 * kk + 1) * C_OUT + c2];
    }
    const __half2* h2 = (const __half2*)hs1h;
    const float2 bb = { b1[2 * c2], b1[2 * c2 + 1] };
    const int waveId = blockIdx.x * 4 + wid;

    for (int node = waveId; node < N_NODES; node += AGG1_BLOCKS * 4) {
        const int beg = rowstart[node], end = rowstart[node + 1];
        float2 acc; acc.x = 0.f; acc.y = 0.f;
        for (int j0 = beg; j0 < end; j0 += 16) {
            const int jj = j0 + eo;
            int idx[8];
#pragma unroll
            for (int s = 0; s < 8; ++s) {
                int j = jj + 2 * s;
                idx[s] = esrc[j < end ? j : beg];   // clamp: dup load, L1 hit
            }
            float ds[8];
#pragma unroll
            for (int s = 0; s < 8; ++s)
                ds[s] = (jj + 2 * s < end) ? dinv[idx[s]] : 0.f;  // predicate via 0-scale
            float2 v[8];
#pragma unroll
            for (int s = 0; s < 8; ++s)
                v[s] = __half22float2(h2[(size_t)idx[s] * 32 + c2]);
#pragma unroll
            for (int s = 0; s < 8; ++s) {
                acc.x = fmaf(ds[s], v[s].x, acc.x);
                acc.y = fmaf(ds[s], v[s].y, acc.y);
            }
        }
        acc.x += __shfl_xor(acc.x, 32);
        acc.y += __shfl_xor(acc.y, 32);
        // layer-1 epilogue: y = relu(dv*(acc + dv*self) + b)
        const float dv = dinv[node];
        float2 self = __half22float2(h2[(size_t)node * 32 + c2]);
        float2 y;
        y.x = fmaxf(fmaf(dv, fmaf(dv, self.x, acc.x), bb.x), 0.f);
        y.y = fmaxf(fmaf(dv, fmaf(dv, self.y, acc.y), bb.y), 0.f);
        yrow[wid][c2] = y;              // both halves write same value (benign)
        __builtin_amdgcn_wave_barrier();
        // layer-2 matvec: out[c2] = Σ_k y[k] * W2[k][c2], k-half per eo
        float o = 0.f;
#pragma unroll
        for (int kk = 0; kk < 16; ++kk) {
            float2 yv = yrow[wid][16 * eo + kk];
            o = fmaf(yv.x, Wreg[2 * kk], o);
            o = fmaf(yv.y, Wreg[2 * kk + 1], o);
        }
        __builtin_amdgcn_wave_barrier();
        o += __shfl_xor(o, 32);
        if (eo == 0)
            hs2h[(size_t)node * C_OUT + c2] = __float2half(o * dv);
    }
}

// ---------------------------------------------------------------------------
// Agg2 (+fused epilogue, no relu). Unchanged from R10 (1 line/edge, ~25 us,
// at the same random-line ceiling).
// ---------------------------------------------------------------------------
__global__ __launch_bounds__(256) void k_agg2(const int* __restrict__ rowstart,
                                              const int* __restrict__ esrc,
                                              const __half* __restrict__ hs2h,
                                              const float* __restrict__ dinv,
                                              const float* __restrict__ b2,
                                              float* __restrict__ out) {
    const int node = blockIdx.x * 4 + (threadIdx.x >> 6);
    const int lane = threadIdx.x & 63;
    const int c2 = lane & 15;
    const int eo = lane >> 4;
    const __half2* h2 = (const __half2*)hs2h;
    const int beg = rowstart[node], end = rowstart[node + 1];
    float2 acc; acc.x = 0.f; acc.y = 0.f;
    for (int j0 = beg; j0 < end; j0 += 16) {
        const int jj = j0 + eo;
        int idx[4];
#pragma unroll
        for (int s = 0; s < 4; ++s) {
            int j = jj + 4 * s;
            idx[s] = esrc[j < end ? j : beg];
        }
        float2 v[4];
#pragma unroll
        for (int s = 0; s < 4; ++s)
            v[s] = __half22float2(h2[(size_t)idx[s] * 16 + c2]);
#pragma unroll
        for (int s = 0; s < 4; ++s) {
            if (jj + 4 * s < end) { acc.x += v[s].x; acc.y += v[s].y; }
        }
    }
    acc.x += __shfl_xor(acc.x, 16);
    acc.y += __shfl_xor(acc.y, 16);
    acc.x += __shfl_xor(acc.x, 32);
    acc.y += __shfl_xor(acc.y, 32);
    if (eo == 0) {
        float2 self = __half22float2(h2[(size_t)node * 16 + c2]);
        float dv = dinv[node];
        float2 o;
        o.x = fmaf(dv, acc.x + self.x, b2[2 * c2]);
        o.y = fmaf(dv, acc.y + self.y, b2[2 * c2 + 1]);
        reinterpret_cast<float2*>(out)[(size_t)node * 16 + c2] = o;
    }
}

extern "C" void kernel_launch(void* const* d_in, const int* in_sizes, int n_in,
                              void* d_out, int out_size, void* d_ws, size_t ws_size,
                              hipStream_t stream) {
    const float* x  = (const float*)d_in[0];
    const unsigned int* ei = (const unsigned int*)d_in[1];
    const float* W1 = (const float*)d_in[2];
    const float* b1 = (const float*)d_in[3];
    const float* W2 = (const float*)d_in[4];
    const float* b2 = (const float*)d_in[5];
    float* out = (float*)d_out;

    char* ws = (char*)d_ws;
    size_t off = 0;
    auto take = [&](size_t bytes) {
        char* p = ws + off;
        off += (bytes + 255) & ~(size_t)255;
        return p;
    };
    int*    esrc     = (int*)   take((size_t)N_EDGES * 4);
    int*    rank     = (int*)   take((size_t)N_EDGES * 4);
    int*    deg      = (int*)   take((size_t)N_NODES * 4);
    int*    rowstart = (int*)   take((size_t)(N_NODES + 1) * 4);
    float*  dinv     = (float*) take((size_t)N_NODES * 4);
    __half* hs1h     = (__half*)take((size_t)N_NODES * C_HID * 2);
    __half* hs2h     = (__half*)take((size_t)N_NODES * C_OUT * 2);

    // op1: zero deg
    hipMemsetAsync(deg, 0, (size_t)N_NODES * 4, stream);

    // op2: rank ∥ gemm1 (independent; co-resident block populations)
    k_rg1<<<RG_GRID, 256, 0, stream>>>(ei, deg, rank, x, W1, hs1h);

    // op3: CSR offsets in ONE single-block kernel (no cross-block sync)
    k_scanone<<<1, 1024, 0, stream>>>(deg, rowstart, dinv);

    // op4: atomic-free fill with non-temporal scatter stores (1024 blocks)
    k_fill2<<<1024, 256, 0, stream>>>(ei, rowstart, rank, esrc);

    // op5: agg1 + epilogue1 + gemm2  (y1 never hits global memory)
    k_agg1g2<<<AGG1_BLOCKS, 256, 0, stream>>>(rowstart, esrc, hs1h, dinv, b1, W2, hs2h);

    // op6: agg2 + epilogue
    k_agg2<<<N_NODES / 4, 256, 0, stream>>>(rowstart, esrc, hs2h, dinv, b2, out);
}